// Round 2
// baseline (2005.054 us; speedup 1.0000x reference)
//
#include <hip/hip_runtime.h>
#include <math.h>

#define BB 32
#define TT 32
#define D_INX 128
#define NSLOT 512
#define MLEN 64
#define NREAD 4
#define NHEAD 5          // 4 read + 1 write
#define CDIM 256
#define KCTRL 384        // D_IN + NUM_READ*M_LEN
#define IDIM 478
#define RHL 70
#define MSTR 66          // Mem row stride in floats: even (float2 align), !=0 mod 32 (bank spread)

// LDS overlay: 163712 B <= 163840 B (160 KiB). One block per CU.
struct SMem {
    float mem[NSLOT * MSTR];     // 135168 B, padded rows
    float wprev[NHEAD * NSLOT];  // 10240 B  persistent addresses
    float mn[NSLOT];             //  2048 B  row norms
    float r[NREAD * MLEN];       //  1024 B  read vectors
    float ctrl[KCTRL];           //  1536 B
    float h[CDIM];               //  1024 B
    float instr[480];            //  1920 B
    float e[MLEN];               //   256 B
    float a[MLEN];               //   256 B
    union {
        float red1[8 * 256];         // GEMV1 partials  8192 B
        float red2[4 * IDIM];        // GEMV2 partials  7648 B
        float wbuf[NHEAD * NSLOT];   // raw sim dots   10240 B
        float rpart[8 * 4 * 64];     // read partials   8192 B
    } u;                         // 10240 B
};

__global__ __launch_bounds__(1024, 4)
void ntm_kernel(const float* __restrict__ x,
                const float* __restrict__ Wc,
                const float* __restrict__ bc,
                const float* __restrict__ Hk,
                const float* __restrict__ hb,
                float* __restrict__ out)
{
    extern __shared__ float smem_f[];
    SMem* sc = (SMem*)smem_f;

    const int b    = blockIdx.x;
    const int tid  = threadIdx.x;
    const int lane = tid & 63;
    const int wave = tid >> 6;     // 0..15

    // ---- zero persistent LDS state ----
    for (int i = tid; i < NSLOT * MSTR; i += 1024) sc->mem[i] = 0.f;
    for (int i = tid; i < NHEAD * NSLOT; i += 1024) sc->wprev[i] = 0.f;
    for (int i = tid; i < NSLOT; i += 1024) sc->mn[i] = 0.f;
    for (int i = tid; i < NREAD * MLEN; i += 1024) sc->r[i] = 0.f;
    __syncthreads();

    for (int t = 0; t < TT; ++t) {
        // ---- stage ctrl_in = [x_t, r] ----
        if (tid < D_INX) sc->ctrl[tid] = x[((size_t)b * TT + t) * D_INX + tid];
        else if (tid < KCTRL) sc->ctrl[tid] = sc->r[tid - D_INX];
        __syncthreads();                                           // B1

        // ---- GEMV1: h_pre = ctrl @ Wc. col-pair p (128 pairs), K-split 8x48 ----
        {
            int p = tid & 127, kb = tid >> 7;
            int i0 = kb * 48;
            const float* wbase = Wc + (size_t)i0 * CDIM + p * 2;
            float ax = 0.f, ay = 0.f, bx = 0.f, by = 0.f;
            for (int ib = 0; ib < 48; ib += 16) {
                float2 wv[16];
#pragma unroll
                for (int q = 0; q < 16; ++q)
                    wv[q] = *(const float2*)(wbase + (size_t)(ib + q) * CDIM);
#pragma unroll
                for (int q = 0; q < 16; ++q) {
                    float c = sc->ctrl[i0 + ib + q];
                    if (q & 1) { bx += c * wv[q].x; by += c * wv[q].y; }
                    else       { ax += c * wv[q].x; ay += c * wv[q].y; }
                }
            }
            ((float2*)sc->u.red1)[kb * 128 + p] = make_float2(ax + bx, ay + by);
        }
        __syncthreads();                                           // B2

        // ---- reduce + tanh ----
        float hv = 0.f;
        if (tid < CDIM) {
            float v = bc[tid];
#pragma unroll
            for (int kb = 0; kb < 8; ++kb) v += sc->u.red1[kb * 256 + tid];
            hv = tanhf(v);
            sc->h[tid] = hv;
        }
        if (t == TT - 1) {             // output is h at last step
            if (tid < CDIM) out[b * CDIM + tid] = hv;
            break;
        }
        __syncthreads();                                           // B3

        // ---- GEMV2: instr = h @ Hk. col-pair p (239 pairs), K-split 4x64 ----
        {
            int p = tid & 255, kb = tid >> 8;
            if (p < 239) {
                int i0 = kb * 64;
                const float* hbase = Hk + (size_t)i0 * IDIM + p * 2;
                float ax = 0.f, ay = 0.f, bx = 0.f, by = 0.f;
                for (int ib = 0; ib < 64; ib += 16) {
                    float2 wv[16];
#pragma unroll
                    for (int q = 0; q < 16; ++q)
                        wv[q] = *(const float2*)(hbase + (size_t)(ib + q) * IDIM);
#pragma unroll
                    for (int q = 0; q < 16; ++q) {
                        float c = sc->h[i0 + ib + q];
                        if (q & 1) { bx += c * wv[q].x; by += c * wv[q].y; }
                        else       { ax += c * wv[q].x; ay += c * wv[q].y; }
                    }
                }
                ((float2*)(sc->u.red2 + (size_t)kb * IDIM))[p] = make_float2(ax + bx, ay + by);
            }
        }
        __syncthreads();                                           // B4

        if (tid < IDIM) {
            float v = hb[tid];
#pragma unroll
            for (int kb = 0; kb < 4; ++kb) v += sc->u.red2[kb * IDIM + tid];
            sc->instr[tid] = v;
        }
        __syncthreads();                                           // B5

        // ---- sim pass: raw dots k_h . Mem[n], row read once for all 5 heads ----
        {
            int n = tid >> 1, m0 = (tid & 1) * 32;
            const float* rowp = sc->mem + n * MSTR + m0;
            float mv[32];
#pragma unroll
            for (int q = 0; q < 16; ++q) ((float2*)mv)[q] = ((const float2*)rowp)[q];
#pragma unroll
            for (int hh = 0; hh < NHEAD; ++hh) {
                const float* kk = sc->instr + hh * RHL + m0;
                float d = 0.f;
#pragma unroll
                for (int j = 0; j < 32; ++j) d += mv[j] * kk[j];
                d += __shfl_xor(d, 1);
                if ((tid & 1) == 0) sc->u.wbuf[hh * NSLOT + n] = d;
            }
        }
        __syncthreads();                                           // B6

        // ---- addressing: one wave per head, all reductions in-wave ----
        if (wave < NHEAD) {
            const int h = wave;
            const float* ins = sc->instr + h * RHL;
            // k-norm
            float kv = ins[lane];
            float sq = kv * kv;
#pragma unroll
            for (int off = 32; off; off >>= 1) sq += __shfl_xor(sq, off);
            float kn = sqrtf(sq);
            float beta = expf(ins[64]);
            float g = 1.f / (1.f + expf(-ins[65]));
            float v0 = ins[66], v1 = ins[67], v2 = ins[68];
            float mx3 = fmaxf(v0, fmaxf(v1, v2));
            float e0 = expf(v0 - mx3), e1 = expf(v1 - mx3), e2 = expf(v2 - mx3);
            float inv3 = 1.f / (e0 + e1 + e2);
            float s0 = e0 * inv3, s1 = e1 * inv3, s2 = e2 * inv3;
            float tv = ins[69];
            float tp = fmaxf(tv, 0.f) + log1pf(expf(-fabsf(tv))) + 1.f;

            // u = beta * sim  (slot = j*64 + lane)
            float uu[8];
#pragma unroll
            for (int j = 0; j < 8; ++j) {
                int slot = j * 64 + lane;
                float d = sc->u.wbuf[h * NSLOT + slot];
                uu[j] = beta * d / (kn * sc->mn[slot] + 1e-8f);
            }
            // softmax over 512 slots
            float m = uu[0];
#pragma unroll
            for (int j = 1; j < 8; ++j) m = fmaxf(m, uu[j]);
#pragma unroll
            for (int off = 32; off; off >>= 1) m = fmaxf(m, __shfl_xor(m, off));
            float ev[8]; float Z = 0.f;
#pragma unroll
            for (int j = 0; j < 8; ++j) { ev[j] = expf(uu[j] - m); Z += ev[j]; }
#pragma unroll
            for (int off = 32; off; off >>= 1) Z += __shfl_xor(Z, off);
            float invZ = 1.f / Z;
            // gate
            float wg[8];
#pragma unroll
            for (int j = 0; j < 8; ++j) {
                int slot = j * 64 + lane;
                wg[j] = g * ev[j] * invZ + (1.f - g) * sc->wprev[h * NSLOT + slot];
            }
            // shift: wsh[n] = s0*wg[n+1] + s1*wg[n] + s2*wg[n-1]  (mod 512)
            int lm = (lane + 63) & 63, lp = (lane + 1) & 63;
            float rm[8], rp[8], b63[8], b0[8];
#pragma unroll
            for (int j = 0; j < 8; ++j) {
                rm[j]  = __shfl(wg[j], lm);
                rp[j]  = __shfl(wg[j], lp);
                b63[j] = __shfl(wg[j], 63);
                b0[j]  = __shfl(wg[j], 0);
            }
            if (lane == 0) {
#pragma unroll
                for (int j = 0; j < 8; ++j) rm[j] = b63[(j + 7) & 7];
            }
            if (lane == 63) {
#pragma unroll
                for (int j = 0; j < 8; ++j) rp[j] = b0[(j + 1) & 7];
            }
            // sharpen + renorm
            float wt[8]; float S = 0.f;
#pragma unroll
            for (int j = 0; j < 8; ++j) {
                float wsh = s0 * rp[j] + s1 * wg[j] + s2 * rm[j];
                wt[j] = powf(wsh, tp);
                S += wt[j];
            }
#pragma unroll
            for (int off = 32; off; off >>= 1) S += __shfl_xor(S, off);
            float invS = 1.f / (S + 1e-8f);
#pragma unroll
            for (int j = 0; j < 8; ++j)
                sc->wprev[h * NSLOT + j * 64 + lane] = wt[j] * invS;
        } else if (wave == 5) {
            sc->e[lane] = sc->instr[350 + lane];
            sc->a[lane] = sc->instr[414 + lane];
        }
        __syncthreads();                                           // B7

        // ---- erase/add update + fused row norm ----
        {
            int n = tid >> 1, m0 = (tid & 1) * 32;
            float* rowp = sc->mem + n * MSTR + m0;
            float wv = sc->wprev[4 * NSLOT + n];
            float mv[32];
#pragma unroll
            for (int q = 0; q < 16; ++q) ((float2*)mv)[q] = ((const float2*)rowp)[q];
            float nsq = 0.f;
#pragma unroll
            for (int j = 0; j < 32; ++j) {
                float nv = mv[j] * (1.f - wv * sc->e[m0 + j]) + wv * sc->a[m0 + j];
                mv[j] = nv;
                nsq += nv * nv;
            }
#pragma unroll
            for (int q = 0; q < 16; ++q) ((float2*)rowp)[q] = ((float2*)mv)[q];
            nsq += __shfl_xor(nsq, 1);
            if ((tid & 1) == 0) sc->mn[n] = sqrtf(nsq);
        }
        __syncthreads();                                           // B8

        // ---- read pass: r[h] = sum_n w[h][n] Mem[n,:], 8 wave-chunks of 64 rows ----
        if (wave < 8) {
            int n0 = wave * 64;
            float a0 = 0.f, a1 = 0.f, a2 = 0.f, a3 = 0.f;
#pragma unroll 8
            for (int n = n0; n < n0 + 64; ++n) {
                float mv = sc->mem[n * MSTR + lane];
                a0 += sc->wprev[0 * NSLOT + n] * mv;
                a1 += sc->wprev[1 * NSLOT + n] * mv;
                a2 += sc->wprev[2 * NSLOT + n] * mv;
                a3 += sc->wprev[3 * NSLOT + n] * mv;
            }
            sc->u.rpart[wave * 256 + 0 * 64 + lane] = a0;
            sc->u.rpart[wave * 256 + 1 * 64 + lane] = a1;
            sc->u.rpart[wave * 256 + 2 * 64 + lane] = a2;
            sc->u.rpart[wave * 256 + 3 * 64 + lane] = a3;
        }
        __syncthreads();                                           // B9

        if (tid < NREAD * MLEN) {
            float s = 0.f;
#pragma unroll
            for (int w = 0; w < 8; ++w) s += sc->u.rpart[w * 256 + tid];
            sc->r[tid] = s;
        }
        __syncthreads();                                           // B10
    }
}

extern "C" void kernel_launch(void* const* d_in, const int* in_sizes, int n_in,
                              void* d_out, int out_size, void* d_ws, size_t ws_size,
                              hipStream_t stream) {
    const float* x  = (const float*)d_in[0];
    const float* Wc = (const float*)d_in[1];
    const float* bc = (const float*)d_in[2];
    const float* Hk = (const float*)d_in[3];
    const float* hb = (const float*)d_in[4];
    float* out = (float*)d_out;

    static_assert(sizeof(SMem) <= 163840, "LDS overflow");
    (void)hipFuncSetAttribute((const void*)ntm_kernel,
                              hipFuncAttributeMaxDynamicSharedMemorySize,
                              (int)sizeof(SMem));
    hipLaunchKernelGGL(ntm_kernel, dim3(BB), dim3(1024), sizeof(SMem), stream,
                       x, Wc, bc, Hk, hb, out);
}

// Round 4
// 1279.885 us; speedup vs baseline: 1.5666x; 1.5666x over previous
//
#include <hip/hip_runtime.h>
#include <math.h>

#define BB 32
#define TT 32
#define D_INX 128
#define NSLOT 512
#define MLEN 64
#define NREAD 4
#define NHEAD 5
#define CDIM 256
#define IDIM 478
#define RHL 70
#define MSTR 66   // Mem row stride (floats): even for b64, 66%32=2 for bank spread

// ws layout: WcT packed fp32 [96 blocks][256 cols][4] = 393216 B at offset 0
//            HkT packed fp32 [64 blocks][478 cols][4] = 489472 B at offset 393216
#define WCT_F4_STRIDE 256
#define HKT_F4_STRIDE 478

struct SMem {
    float mem[NSLOT * MSTR];     // 135168
    float wprev[NHEAD * NSLOT];  //  10240
    float mn[NSLOT];             //   2048
    float r[NREAD * MLEN];       //   1024
    float h[CDIM];               //   1024
    float instr[480];            //   1920
    float e[MLEN];               //    256
    float a[MLEN];               //    256
    float k[NHEAD * MLEN];       //   1280  16B-aligned k matrix for b128 reads
    float ubuf[2560];            //  10240  wbuf(0..2559) | rpart(0..2047) | x(2176..2303)
};                               // total 163456 <= 163840

#define UX(sc)    ((sc)->ubuf + 2176)
#define WBUF(sc)  ((sc)->ubuf)
#define RPART(sc) ((sc)->ubuf)

__global__ void pack_kernel(const float* __restrict__ Wc, const float* __restrict__ Hk,
                            float* __restrict__ wct, float* __restrict__ hkt)
{
    int idx = blockIdx.x * 256 + threadIdx.x;
    if (idx < 384 * 256) {
        int i = idx >> 8, j = idx & 255;
        wct[(i >> 2) * (WCT_F4_STRIDE * 4) + j * 4 + (i & 3)] = Wc[idx];
    }
    if (idx < 256 * 478) {
        int i = idx / 478, j = idx - i * 478;
        hkt[(i >> 2) * (HKT_F4_STRIDE * 4) + j * 4 + (i & 3)] = Hk[idx];
    }
}

__global__ __launch_bounds__(1024, 4)
void ntm_kernel(const float* __restrict__ x,
                const float* __restrict__ bc,
                const float* __restrict__ hb,
                const float* __restrict__ wct,
                const float* __restrict__ hkt,
                float* __restrict__ out)
{
    extern __shared__ float smem_f[];
    SMem* sc = (SMem*)smem_f;

    const int b    = blockIdx.x;
    const int tid  = threadIdx.x;
    const int lane = tid & 63;
    const int wave = tid >> 6;

    // ---- prologue: zero persistent state, stage x[t=0] ----
    for (int i = tid; i < NSLOT * MSTR; i += 1024) sc->mem[i] = 0.f;
    for (int i = tid; i < NHEAD * NSLOT; i += 1024) sc->wprev[i] = 0.f;
    for (int i = tid; i < NSLOT; i += 1024) sc->mn[i] = 0.f;
    if (tid < NREAD * MLEN) sc->r[tid] = 0.f;
    if (tid < D_INX) UX(sc)[tid] = x[((size_t)b * TT + 0) * D_INX + tid];
    __syncthreads();

    for (int t = 0; t < TT; ++t) {
        // ---- P1: GEMV1 full-dot per column + tanh -> s_h ----
        if (tid < CDIM) {
            const float4* wq = ((const float4*)wct) + tid;
            const float4* xs4 = (const float4*)UX(sc);
            const float4* rr4 = (const float4*)sc->r;
            float acc0 = bc[tid], acc1 = 0.f;
#pragma unroll
            for (int q = 0; q < 32; q += 2) {
                float4 w0 = wq[q * WCT_F4_STRIDE], c0 = xs4[q];
                float4 w1 = wq[(q + 1) * WCT_F4_STRIDE], c1 = xs4[q + 1];
                acc0 += w0.x * c0.x + w0.y * c0.y + w0.z * c0.z + w0.w * c0.w;
                acc1 += w1.x * c1.x + w1.y * c1.y + w1.z * c1.z + w1.w * c1.w;
            }
#pragma unroll
            for (int q = 32; q < 96; q += 2) {
                float4 w0 = wq[q * WCT_F4_STRIDE], c0 = rr4[q - 32];
                float4 w1 = wq[(q + 1) * WCT_F4_STRIDE], c1 = rr4[q - 31];
                acc0 += w0.x * c0.x + w0.y * c0.y + w0.z * c0.z + w0.w * c0.w;
                acc1 += w1.x * c1.x + w1.y * c1.y + w1.z * c1.z + w1.w * c1.w;
            }
            float hv = tanhf(acc0 + acc1);
            sc->h[tid] = hv;
            if (t == TT - 1) out[(size_t)b * CDIM + tid] = hv;
        }
        if (t == TT - 1) break;
        __syncthreads();                                      // B1

        // ---- P2: GEMV2 full-dot per column -> instr; stage k/e/a in-phase ----
        if (tid < IDIM) {
            const float4* wq = ((const float4*)hkt) + tid;
            const float4* h4 = (const float4*)sc->h;
            float acc0 = hb[tid], acc1 = 0.f;
#pragma unroll
            for (int q = 0; q < 64; q += 2) {
                float4 w0 = wq[q * HKT_F4_STRIDE], c0 = h4[q];
                float4 w1 = wq[(q + 1) * HKT_F4_STRIDE], c1 = h4[q + 1];
                acc0 += w0.x * c0.x + w0.y * c0.y + w0.z * c0.z + w0.w * c0.w;
                acc1 += w1.x * c1.x + w1.y * c1.y + w1.z * c1.z + w1.w * c1.w;
            }
            float v = acc0 + acc1;
            sc->instr[tid] = v;
            if (tid < 350) {
                int hh = (tid * 937) >> 16;       // tid/70 for tid<350
                int m = tid - hh * RHL;
                if (m < MLEN) sc->k[hh * MLEN + m] = v;
            } else if (tid < 414) {
                sc->e[tid - 350] = v;
            } else {
                sc->a[tid - 414] = v;
            }
        }
        __syncthreads();                                      // B2

        // ---- P3: sim pass (raw dots), k via b128 broadcasts ----
        {
            int n = tid >> 1, m0 = (tid & 1) * 32;
            const float2* rp = (const float2*)(sc->mem + n * MSTR + m0);
            float mv[32];
#pragma unroll
            for (int q = 0; q < 16; ++q) ((float2*)mv)[q] = rp[q];
#pragma unroll
            for (int hh = 0; hh < NHEAD; ++hh) {
                const float4* kp = (const float4*)(sc->k + hh * MLEN + m0);
                float d = 0.f;
#pragma unroll
                for (int q = 0; q < 8; ++q) {
                    float4 kv = kp[q];
                    d += mv[4 * q] * kv.x + mv[4 * q + 1] * kv.y
                       + mv[4 * q + 2] * kv.z + mv[4 * q + 3] * kv.w;
                }
                d += __shfl_xor(d, 1);
                if ((tid & 1) == 0) WBUF(sc)[hh * NSLOT + n] = d;
            }
        }
        __syncthreads();                                      // B3

        // ---- P4: addressing, one wave per head ----
        if (wave < NHEAD) {
            const int h = wave;
            const float* ins = sc->instr + h * RHL;
            float kv = ins[lane];
            float sq = kv * kv;
#pragma unroll
            for (int off = 32; off; off >>= 1) sq += __shfl_xor(sq, off);
            float kn = sqrtf(sq);
            float beta = __expf(ins[64]);
            float g = 1.f / (1.f + __expf(-ins[65]));
            float v0 = ins[66], v1 = ins[67], v2 = ins[68];
            float mx3 = fmaxf(v0, fmaxf(v1, v2));
            float e0 = __expf(v0 - mx3), e1 = __expf(v1 - mx3), e2 = __expf(v2 - mx3);
            float inv3 = 1.f / (e0 + e1 + e2);
            float s0 = e0 * inv3, s1 = e1 * inv3, s2 = e2 * inv3;
            float tv = ins[69];
            float tp = fmaxf(tv, 0.f) + log1pf(__expf(-fabsf(tv))) + 1.f;

            float uu[8];
#pragma unroll
            for (int j = 0; j < 8; ++j) {
                int slot = j * 64 + lane;
                float d = WBUF(sc)[h * NSLOT + slot];
                uu[j] = beta * d / (kn * sc->mn[slot] + 1e-8f);
            }
            float m = uu[0];
#pragma unroll
            for (int j = 1; j < 8; ++j) m = fmaxf(m, uu[j]);
#pragma unroll
            for (int off = 32; off; off >>= 1) m = fmaxf(m, __shfl_xor(m, off));
            float ev[8]; float Z = 0.f;
#pragma unroll
            for (int j = 0; j < 8; ++j) { ev[j] = __expf(uu[j] - m); Z += ev[j]; }
#pragma unroll
            for (int off = 32; off; off >>= 1) Z += __shfl_xor(Z, off);
            float invZ = 1.f / Z;
            float wg[8];
#pragma unroll
            for (int j = 0; j < 8; ++j) {
                int slot = j * 64 + lane;
                wg[j] = g * ev[j] * invZ + (1.f - g) * sc->wprev[h * NSLOT + slot];
            }
            int lm = (lane + 63) & 63, lp = (lane + 1) & 63;
            float rm[8], rp[8], b63[8], b0[8];
#pragma unroll
            for (int j = 0; j < 8; ++j) {
                rm[j]  = __shfl(wg[j], lm);
                rp[j]  = __shfl(wg[j], lp);
                b63[j] = __shfl(wg[j], 63);
                b0[j]  = __shfl(wg[j], 0);
            }
            if (lane == 0) {
#pragma unroll
                for (int j = 0; j < 8; ++j) rm[j] = b63[(j + 7) & 7];
            }
            if (lane == 63) {
#pragma unroll
                for (int j = 0; j < 8; ++j) rp[j] = b0[(j + 1) & 7];
            }
            float wt[8]; float S = 0.f;
#pragma unroll
            for (int j = 0; j < 8; ++j) {
                float wsh = s0 * rp[j] + s1 * wg[j] + s2 * rm[j];
                // pow(wsh, tp) = exp2(tp * log2(wsh)); wsh>=0, log2(0)=-inf -> exp2(-inf)=0
                wt[j] = __builtin_amdgcn_exp2f(tp * __builtin_amdgcn_logf(wsh));
                S += wt[j];
            }
#pragma unroll
            for (int off = 32; off; off >>= 1) S += __shfl_xor(S, off);
            float invS = 1.f / (S + 1e-8f);
#pragma unroll
            for (int j = 0; j < 8; ++j)
                sc->wprev[h * NSLOT + j * 64 + lane] = wt[j] * invS;
        }
        __syncthreads();                                      // B4

        // ---- P5: erase/add update + fused row norm ----
        {
            int n = tid >> 1, m0 = (tid & 1) * 32;
            float* rowp = sc->mem + n * MSTR + m0;
            float wv = sc->wprev[4 * NSLOT + n];
            float mv[32], evv[32], avv[32];
#pragma unroll
            for (int q = 0; q < 16; ++q) ((float2*)mv)[q] = ((const float2*)rowp)[q];
#pragma unroll
            for (int q = 0; q < 8; ++q) ((float4*)evv)[q] = ((const float4*)(sc->e + m0))[q];
#pragma unroll
            for (int q = 0; q < 8; ++q) ((float4*)avv)[q] = ((const float4*)(sc->a + m0))[q];
            float nsq = 0.f;
#pragma unroll
            for (int j = 0; j < 32; ++j) {
                float nv = mv[j] * (1.f - wv * evv[j]) + wv * avv[j];
                mv[j] = nv;
                nsq += nv * nv;
            }
#pragma unroll
            for (int q = 0; q < 16; ++q) ((float2*)rowp)[q] = ((float2*)mv)[q];
            nsq += __shfl_xor(nsq, 1);
            if ((tid & 1) == 0) sc->mn[n] = sqrtf(nsq);
        }
        __syncthreads();                                      // B5

        // ---- P6: read pass, 2 rows per b64 instruction ----
        if (wave < 8) {
            int base = wave * 64;
            int half = lane >> 5, c = lane & 31;
            float a0x = 0.f, a0y = 0.f, a1x = 0.f, a1y = 0.f;
            float a2x = 0.f, a2y = 0.f, a3x = 0.f, a3y = 0.f;
#pragma unroll 8
            for (int i = 0; i < 32; ++i) {
                int n = base + 2 * i + half;
                float2 mv = *(const float2*)(sc->mem + n * MSTR + 2 * c);
                float w0 = sc->wprev[0 * NSLOT + n];
                float w1 = sc->wprev[1 * NSLOT + n];
                float w2 = sc->wprev[2 * NSLOT + n];
                float w3 = sc->wprev[3 * NSLOT + n];
                a0x += w0 * mv.x; a0y += w0 * mv.y;
                a1x += w1 * mv.x; a1y += w1 * mv.y;
                a2x += w2 * mv.x; a2y += w2 * mv.y;
                a3x += w3 * mv.x; a3y += w3 * mv.y;
            }
            a0x += __shfl_xor(a0x, 32); a0y += __shfl_xor(a0y, 32);
            a1x += __shfl_xor(a1x, 32); a1y += __shfl_xor(a1y, 32);
            a2x += __shfl_xor(a2x, 32); a2y += __shfl_xor(a2y, 32);
            a3x += __shfl_xor(a3x, 32); a3y += __shfl_xor(a3y, 32);
            if (lane < 32) {
                float* rb = RPART(sc) + wave * 256;
                ((float2*)(rb + 0 * 64))[c] = make_float2(a0x, a0y);
                ((float2*)(rb + 1 * 64))[c] = make_float2(a1x, a1y);
                ((float2*)(rb + 2 * 64))[c] = make_float2(a2x, a2y);
                ((float2*)(rb + 3 * 64))[c] = make_float2(a3x, a3y);
            }
        }
        __syncthreads();                                      // B6

        // ---- P7: r-reduce + stage x[t+1] ----
        if (tid < NREAD * MLEN) {
            float s = 0.f;
#pragma unroll
            for (int w = 0; w < 8; ++w) s += RPART(sc)[w * 256 + tid];
            sc->r[tid] = s;
        } else if (tid < 384) {
            UX(sc)[tid - 256] = x[((size_t)b * TT + t + 1) * D_INX + (tid - 256)];
        }
        __syncthreads();                                      // B7
    }
}

extern "C" void kernel_launch(void* const* d_in, const int* in_sizes, int n_in,
                              void* d_out, int out_size, void* d_ws, size_t ws_size,
                              hipStream_t stream) {
    const float* x  = (const float*)d_in[0];
    const float* Wc = (const float*)d_in[1];
    const float* bc = (const float*)d_in[2];
    const float* Hk = (const float*)d_in[3];
    const float* hb = (const float*)d_in[4];
    float* out = (float*)d_out;

    float* wct = (float*)d_ws;                       // 393216 B
    float* hkt = (float*)((char*)d_ws + 393216);     // 489472 B

    static_assert(sizeof(SMem) <= 163840, "LDS overflow");
    (void)hipFuncSetAttribute((const void*)ntm_kernel,
                              hipFuncAttributeMaxDynamicSharedMemorySize,
                              (int)sizeof(SMem));

    hipLaunchKernelGGL(pack_kernel, dim3(478), dim3(256), 0, stream, Wc, Hk, wct, hkt);
    hipLaunchKernelGGL(ntm_kernel, dim3(BB), dim3(1024), sizeof(SMem), stream,
                       x, bc, hb, wct, hkt, out);
}

// Round 5
// 905.427 us; speedup vs baseline: 2.2145x; 1.4136x over previous
//
#include <hip/hip_runtime.h>
#include <math.h>

#define BB 32
#define TT 32
#define D_INX 128
#define NSLOT 512
#define MLEN 64
#define NREAD 4
#define NHEAD 5
#define CDIM 256
#define IDIM 478
#define RHL 70
#define NT 512          // threads per block (8 waves)

// d_ws: wctb bf16 [48 chunks][256 cols][8] = 196608 B @ 0
//       hkb  bf16 [32 chunks][478 cols][8] = 244736 B @ 196608
#define HKB_OFF 196608

struct SMem {
    float mem[NSLOT * MLEN];     // 131072 B — XOR-swizzled: logical f4 j of row n at slot j^(n&15)
    float wprev[NHEAD * NSLOT];  //  10240
    float mn[NSLOT];             //   2048
    float ctrl[384];             //   1536  [x(128) | r(256)]
    float h[CDIM];               //   1024
    float instr[480];            //   1920
    float k[NHEAD * MLEN];       //   1280
    float e[MLEN];               //    256
    float a[MLEN];               //    256
    float u[2560];               //  10240  red(512) | wbuf(2560) | rpart(2048)
};                               // 159872 B <= 163840

__device__ __forceinline__ unsigned short f2bf(float f) {
    unsigned u = __float_as_uint(f);
    return (unsigned short)((u + 0x7fffu + ((u >> 16) & 1u)) >> 16);
}

__global__ void pack_kernel(const float* __restrict__ Wc, const float* __restrict__ Hk,
                            unsigned short* __restrict__ wctb, unsigned short* __restrict__ hkb)
{
    int idx = blockIdx.x * 256 + threadIdx.x;
    if (idx < 384 * 256) {
        int i = idx >> 8, col = idx & 255;
        wctb[((i >> 3) * 256 + col) * 8 + (i & 7)] = f2bf(Wc[idx]);
    }
    if (idx < 256 * 478) {
        int i = idx / 478, col = idx - i * 478;
        hkb[((i >> 3) * 478 + col) * 8 + (i & 7)] = f2bf(Hk[idx]);
    }
}

// acc += (8 bf16 in wv) . (4 float2 from act base)
#define BF8_DOT(wv, c0, c1, c2, c3, acc) do {                                   \
    unsigned _u0 = __float_as_uint((wv).x), _u1 = __float_as_uint((wv).y);      \
    unsigned _u2 = __float_as_uint((wv).z), _u3 = __float_as_uint((wv).w);      \
    acc += __uint_as_float(_u0 << 16) * (c0).x + __uint_as_float(_u0 & 0xffff0000u) * (c0).y; \
    acc += __uint_as_float(_u1 << 16) * (c1).x + __uint_as_float(_u1 & 0xffff0000u) * (c1).y; \
    acc += __uint_as_float(_u2 << 16) * (c2).x + __uint_as_float(_u2 & 0xffff0000u) * (c2).y; \
    acc += __uint_as_float(_u3 << 16) * (c3).x + __uint_as_float(_u3 & 0xffff0000u) * (c3).y; \
} while (0)

__global__ __launch_bounds__(NT, 2)
void ntm_kernel(const float* __restrict__ x,
                const float* __restrict__ bc,
                const float* __restrict__ hb,
                const unsigned short* __restrict__ wctb,
                const unsigned short* __restrict__ hkb,
                float* __restrict__ out)
{
    extern __shared__ float smem_f[];
    SMem* sc = (SMem*)smem_f;

    const int b    = blockIdx.x;
    const int tid  = threadIdx.x;
    const int lane = tid & 63;
    const int wave = tid >> 6;   // 0..7

    const float bcv = (tid < CDIM) ? bc[tid] : 0.f;
    const float hbv = (tid < IDIM) ? hb[tid] : 0.f;

    // ---- prologue ----
    {
        float4 z4 = make_float4(0.f, 0.f, 0.f, 0.f);
        float4* m4 = (float4*)sc->mem;
        for (int i = tid; i < NSLOT * MLEN / 4; i += NT) m4[i] = z4;
        for (int i = tid; i < NHEAD * NSLOT; i += NT) sc->wprev[i] = 0.f;
        sc->mn[tid] = 0.f;
        if (tid < 384) sc->ctrl[tid] = (tid < D_INX) ? x[(size_t)b * TT * D_INX + tid] : 0.f;
    }
    __syncthreads();

    for (int t = 0; t < TT; ++t) {
        // ---- P1a: GEMV1 K-split-2, bf16 weights: partials ----
        {
            int col = tid & 255, kb = tid >> 8;
            const float4* wq = (const float4*)wctb + kb * 24 * 256 + col;
            const float2* c2 = (const float2*)sc->ctrl + kb * 96;
            float acc = 0.f;
#pragma unroll
            for (int cc = 0; cc < 24; ++cc) {
                float4 wv = wq[cc * 256];
                float2 x0 = c2[cc * 4], x1 = c2[cc * 4 + 1], x2 = c2[cc * 4 + 2], x3 = c2[cc * 4 + 3];
                BF8_DOT(wv, x0, x1, x2, x3, acc);
            }
            sc->u[kb * 256 + col] = acc;
        }
        __syncthreads();                                   // B1

        // ---- P1b: combine + tanh -> h; stage x[t+1] ----
        if (tid < CDIM) {
            float hv = tanhf(bcv + sc->u[tid] + sc->u[256 + tid]);
            sc->h[tid] = hv;
            if (t == TT - 1) out[(size_t)b * CDIM + tid] = hv;
        } else if (tid < 384 && t + 1 < TT) {
            sc->ctrl[tid - 256] = x[((size_t)b * TT + t + 1) * D_INX + (tid - 256)];
        }
        if (t == TT - 1) break;
        __syncthreads();                                   // B2

        // ---- P2: GEMV2 full-K bf16 -> instr; scatter k/e/a ----
        if (tid < IDIM) {
            const float4* wq = (const float4*)hkb + tid;
            const float2* h2 = (const float2*)sc->h;
            float acc = hbv;
#pragma unroll
            for (int c = 0; c < 32; ++c) {
                float4 wv = wq[c * 478];
                float2 x0 = h2[c * 4], x1 = h2[c * 4 + 1], x2 = h2[c * 4 + 2], x3 = h2[c * 4 + 3];
                BF8_DOT(wv, x0, x1, x2, x3, acc);
            }
            sc->instr[tid] = acc;
            if (tid < 350) {
                int hh = (tid * 937) >> 16;     // tid/70
                int m = tid - hh * RHL;
                if (m < MLEN) sc->k[hh * MLEN + m] = acc;
            } else if (tid < 414) {
                sc->e[tid - 350] = acc;
            } else {
                sc->a[tid - 414] = acc;
            }
        }
        __syncthreads();                                   // B3

        // ---- P3: sim dots, thread = row, swizzled f4 reads ----
        {
            int n = tid, nx = n & 15;
            const float4* m4 = (const float4*)sc->mem + n * 16;
            const float4* k4 = (const float4*)sc->k;
            float d0 = 0.f, d1 = 0.f, d2 = 0.f, d3 = 0.f, d4 = 0.f;
#pragma unroll
            for (int j = 0; j < 16; ++j) {
                float4 mv = m4[j ^ nx];
                float4 k0 = k4[j], k1 = k4[16 + j], k2 = k4[32 + j], k3 = k4[48 + j], kw = k4[64 + j];
                d0 += mv.x * k0.x + mv.y * k0.y + mv.z * k0.z + mv.w * k0.w;
                d1 += mv.x * k1.x + mv.y * k1.y + mv.z * k1.z + mv.w * k1.w;
                d2 += mv.x * k2.x + mv.y * k2.y + mv.z * k2.z + mv.w * k2.w;
                d3 += mv.x * k3.x + mv.y * k3.y + mv.z * k3.z + mv.w * k3.w;
                d4 += mv.x * kw.x + mv.y * kw.y + mv.z * kw.z + mv.w * kw.w;
            }
            sc->u[n] = d0; sc->u[512 + n] = d1; sc->u[1024 + n] = d2;
            sc->u[1536 + n] = d3; sc->u[2048 + n] = d4;
        }
        __syncthreads();                                   // B4

        // ---- P4: addressing, one wave per head ----
        if (wave < NHEAD) {
            const int h = wave;
            const float* ins = sc->instr + h * RHL;
            float kv = ins[lane];
            float sq = kv * kv;
#pragma unroll
            for (int off = 32; off; off >>= 1) sq += __shfl_xor(sq, off);
            float kn = sqrtf(sq);
            float beta = __expf(ins[64]);
            float g = 1.f / (1.f + __expf(-ins[65]));
            float v0 = ins[66], v1 = ins[67], v2 = ins[68];
            float mx3 = fmaxf(v0, fmaxf(v1, v2));
            float e0 = __expf(v0 - mx3), e1 = __expf(v1 - mx3), e2 = __expf(v2 - mx3);
            float inv3 = 1.f / (e0 + e1 + e2);
            float s0 = e0 * inv3, s1 = e1 * inv3, s2 = e2 * inv3;
            float tv = ins[69];
            float tp = fmaxf(tv, 0.f) + log1pf(__expf(-fabsf(tv))) + 1.f;

            float uu[8];
#pragma unroll
            for (int j = 0; j < 8; ++j) {
                int slot = j * 64 + lane;
                float d = sc->u[h * NSLOT + slot];
                uu[j] = beta * d / (kn * sc->mn[slot] + 1e-8f);
            }
            float m = uu[0];
#pragma unroll
            for (int j = 1; j < 8; ++j) m = fmaxf(m, uu[j]);
#pragma unroll
            for (int off = 32; off; off >>= 1) m = fmaxf(m, __shfl_xor(m, off));
            float ev[8]; float Z = 0.f;
#pragma unroll
            for (int j = 0; j < 8; ++j) { ev[j] = __expf(uu[j] - m); Z += ev[j]; }
#pragma unroll
            for (int off = 32; off; off >>= 1) Z += __shfl_xor(Z, off);
            float invZ = 1.f / Z;
            float wg[8];
#pragma unroll
            for (int j = 0; j < 8; ++j) {
                int slot = j * 64 + lane;
                wg[j] = g * ev[j] * invZ + (1.f - g) * sc->wprev[h * NSLOT + slot];
            }
            int lm = (lane + 63) & 63, lp = (lane + 1) & 63;
            float rm[8], rp[8], b63[8], b0[8];
#pragma unroll
            for (int j = 0; j < 8; ++j) {
                rm[j]  = __shfl(wg[j], lm);
                rp[j]  = __shfl(wg[j], lp);
                b63[j] = __shfl(wg[j], 63);
                b0[j]  = __shfl(wg[j], 0);
            }
            if (lane == 0) {
#pragma unroll
                for (int j = 0; j < 8; ++j) rm[j] = b63[(j + 7) & 7];
            }
            if (lane == 63) {
#pragma unroll
                for (int j = 0; j < 8; ++j) rp[j] = b0[(j + 1) & 7];
            }
            float wt[8]; float S = 0.f;
#pragma unroll
            for (int j = 0; j < 8; ++j) {
                float wsh = s0 * rp[j] + s1 * wg[j] + s2 * rm[j];
                wt[j] = __builtin_amdgcn_exp2f(tp * __builtin_amdgcn_logf(wsh));
                S += wt[j];
            }
#pragma unroll
            for (int off = 32; off; off >>= 1) S += __shfl_xor(S, off);
            float invS = 1.f / (S + 1e-8f);
#pragma unroll
            for (int j = 0; j < 8; ++j)
                sc->wprev[h * NSLOT + j * 64 + lane] = wt[j] * invS;
        }
        __syncthreads();                                   // B5

        // ---- P5: erase/add update + row norm, thread = row ----
        {
            int n = tid, nx = n & 15;
            float4* m4 = (float4*)sc->mem + n * 16;
            const float4* e4 = (const float4*)sc->e;
            const float4* a4 = (const float4*)sc->a;
            float wv = sc->wprev[4 * NSLOT + n];
            float nsq = 0.f;
#pragma unroll
            for (int j = 0; j < 16; ++j) {
                float4 mv = m4[j ^ nx];
                float4 ev = e4[j], av = a4[j];
                mv.x = mv.x * (1.f - wv * ev.x) + wv * av.x;
                mv.y = mv.y * (1.f - wv * ev.y) + wv * av.y;
                mv.z = mv.z * (1.f - wv * ev.z) + wv * av.z;
                mv.w = mv.w * (1.f - wv * ev.w) + wv * av.w;
                nsq += mv.x * mv.x + mv.y * mv.y + mv.z * mv.z + mv.w * mv.w;
                m4[j ^ nx] = mv;
            }
            sc->mn[n] = sqrtf(nsq);
        }
        __syncthreads();                                   // B6

        // ---- P6: read pass: wave w = rows [64w,64w+64), lane = (rowgroup, f4col) ----
        {
            int rg = lane >> 4, j = lane & 15;
            int base = wave * 64;
            float4 ac[4];
#pragma unroll
            for (int hh = 0; hh < 4; ++hh) ac[hh] = make_float4(0.f, 0.f, 0.f, 0.f);
#pragma unroll
            for (int i = 0; i < 16; ++i) {
                int n = base + 4 * i + rg;
                float4 mv = ((const float4*)sc->mem)[n * 16 + (j ^ (n & 15))];
                float w0 = sc->wprev[n], w1 = sc->wprev[512 + n];
                float w2 = sc->wprev[1024 + n], w3 = sc->wprev[1536 + n];
                ac[0].x += w0 * mv.x; ac[0].y += w0 * mv.y; ac[0].z += w0 * mv.z; ac[0].w += w0 * mv.w;
                ac[1].x += w1 * mv.x; ac[1].y += w1 * mv.y; ac[1].z += w1 * mv.z; ac[1].w += w1 * mv.w;
                ac[2].x += w2 * mv.x; ac[2].y += w2 * mv.y; ac[2].z += w2 * mv.z; ac[2].w += w2 * mv.w;
                ac[3].x += w3 * mv.x; ac[3].y += w3 * mv.y; ac[3].z += w3 * mv.z; ac[3].w += w3 * mv.w;
            }
            float* af = (float*)ac;
#pragma unroll
            for (int q = 0; q < 16; ++q) {
                af[q] += __shfl_xor(af[q], 16);
                af[q] += __shfl_xor(af[q], 32);
            }
            if (rg == 0) {
                float4* rp = (float4*)(sc->u + wave * 256);
                rp[0 * 16 + j] = ac[0];
                rp[1 * 16 + j] = ac[1];
                rp[2 * 16 + j] = ac[2];
                rp[3 * 16 + j] = ac[3];
            }
        }
        __syncthreads();                                   // B7

        // ---- P7: r-reduce into ctrl ----
        if (tid < 256) {
            float s = 0.f;
#pragma unroll
            for (int w = 0; w < 8; ++w) s += sc->u[w * 256 + tid];
            sc->ctrl[128 + tid] = s;
        }
        __syncthreads();                                   // B8
    }
}

extern "C" void kernel_launch(void* const* d_in, const int* in_sizes, int n_in,
                              void* d_out, int out_size, void* d_ws, size_t ws_size,
                              hipStream_t stream) {
    const float* x  = (const float*)d_in[0];
    const float* Wc = (const float*)d_in[1];
    const float* bc = (const float*)d_in[2];
    const float* Hk = (const float*)d_in[3];
    const float* hb = (const float*)d_in[4];
    float* out = (float*)d_out;

    unsigned short* wctb = (unsigned short*)d_ws;
    unsigned short* hkb  = (unsigned short*)((char*)d_ws + HKB_OFF);

    static_assert(sizeof(SMem) <= 163840, "LDS overflow");
    (void)hipFuncSetAttribute((const void*)ntm_kernel,
                              hipFuncAttributeMaxDynamicSharedMemorySize,
                              (int)sizeof(SMem));

    hipLaunchKernelGGL(pack_kernel, dim3(478), dim3(256), 0, stream, Wc, Hk, wctb, hkb);
    hipLaunchKernelGGL(ntm_kernel, dim3(BB), dim3(NT), sizeof(SMem), stream,
                       x, bc, hb, wctb, hkb, out);
}